// Round 13
// baseline (171.892 us; speedup 1.0000x reference)
//
#include <hip/hip_runtime.h>
#include <hip/hip_bf16.h>

typedef __attribute__((ext_vector_type(8))) short bf16x8;
typedef __attribute__((ext_vector_type(16))) float f32x16;

#define INH   128
#define LEAK  0.01f
#define GSTR  288          // U row stride in bf16 (15 zero + 256 data + 17 zero)
#define TSTR  200          // LDS tile stride in bf16 (400B; 16B-mult, 8-phase bank spread)
#define TROWS 158          // 128 conv rows + 30 halo

__device__ __forceinline__ unsigned short f2bf(float f) {
    __hip_bfloat16 h = __float2bfloat16(f);
    return *(unsigned short*)&h;
}

__device__ __forceinline__ float upsample_one(const float* __restrict__ xc,
                                              int ur, int uc, float UPS) {
    float cr = (float)ur * UPS;
    int r0 = (int)cr; if (r0 > 126) r0 = 126;
    float wr = cr - (float)r0;
    float cs = (float)uc * UPS;
    int s0 = (int)cs; if (s0 > 126) s0 = 126;
    float ws = cs - (float)s0;
    const float* p = xc + r0 * INH + s0;
    float a = p[0], b = p[1], c = p[INH], d = p[INH + 1];
    float top = a + (c - a) * wr;          // rows first (reference order)
    float bot = b + (d - b) * wr;
    float val = top + (bot - top) * ws;
    return (val > 0.0f) ? val : (LEAK * val);
}

// ---------- table builder (standalone, for fallback path) ----------
__global__ void build_table(const float* __restrict__ filt, unsigned short* __restrict__ tab) {
    int idx = blockIdx.x * 256 + threadIdx.x;          // (fr*4+c)*64 + lane
    if (idx >= 31 * 4 * 64) return;
    int lane = idx & 63, c = (idx >> 6) & 3, fr = idx >> 8;
    #pragma unroll
    for (int t = 0; t < 8; ++t) {
        int v = 16 * c + 8 * (lane >> 5) + t - (lane & 31);
        float f = (v >= 0 && v <= 30) ? filt[fr * 31 + v] : 0.0f;
        tab[idx * 8 + t] = f2bf(f);
    }
}

// ---------- kernel 1: table build (blocks 0..30) + upsample+act -> U (blocks 31..) ----------
__global__ __launch_bounds__(256)
void up_table(const float* __restrict__ x, const float* __restrict__ filt,
              unsigned short* __restrict__ U, unsigned short* __restrict__ tab) {
    const int tid = threadIdx.x;
    if (blockIdx.x < 31) {
        int idx = blockIdx.x * 256 + tid;
        if (idx >= 31 * 4 * 64) return;
        int lane = idx & 63, c = (idx >> 6) & 3, fr = idx >> 8;
        #pragma unroll
        for (int t = 0; t < 8; ++t) {
            int v = 16 * c + 8 * (lane >> 5) + t - (lane & 31);
            float f = (v >= 0 && v <= 30) ? filt[fr * 31 + v] : 0.0f;
            tab[idx * 8 + t] = f2bf(f);
        }
        return;
    }
    const float UPS = (float)(127.0 / 255.0);
    int idx = (blockIdx.x - 31) * 256 + tid;           // unit = 4 bf16 cols (8 B)
    int bc = idx / (256 * 72);
    int rem = idx - bc * (256 * 72);
    int r = rem / 72;
    int c4 = (rem - r * 72) * 4;
    const float* __restrict__ xc = x + (size_t)bc * (INH * INH);
    unsigned short o[4];
    #pragma unroll
    for (int e = 0; e < 4; ++e) {
        int uc = c4 + e - 15;
        float val = 0.0f;
        if ((unsigned)uc < 256u) val = upsample_one(xc, r, uc, UPS);
        o[e] = f2bf(val);
    }
    *(uint2*)&U[((size_t)bc * 256 + r) * GSTR + c4] = *(const uint2*)o;
}

// ---------- kernel 2: copy-stage -> MFMA conv (4-strip waves: 16 MFMA per B-set) -> downsample ----------
// Wave = 32 rows x 128 cols (4 strips of 32). B-frags loaded ONCE per fr feed 16 MFMAs
// (halves VMEM B-traffic vs 2-strip). Block = 4 waves = 128 rows x 128 cols.
__global__ __launch_bounds__(256, 2)
void conv_ds(const unsigned short* __restrict__ U, const unsigned short* __restrict__ tab,
             float* __restrict__ out) {
    __shared__ unsigned short T[TROWS * TSTR];         // 63200 B -> 2 blocks/CU
    const int tid = threadIdx.x;
    const int bx = blockIdx.x;                         // 0..1 (col half, 128 conv cols)
    const int by = blockIdx.y;                         // 0..1 (row half, 128 conv rows)
    const int bc = blockIdx.z;                         // 0..511
    const float DNS = (float)(255.0 / 127.0);
    const unsigned short* __restrict__ Ub = U + (size_t)bc * 256 * GSTR + bx * 128;

    // ---- stage: 158 rows x 20 uint4 (160 bf16 cols = exactly the read span) ----
    #pragma unroll
    for (int k = 0; k < 13; ++k) {
        int c = tid + k * 256;
        if (c < TROWS * 20) {
            int row = c / 20;
            int sub = c - row * 20;
            int gr = 128 * by + row - 15;
            uint4 v = {0u, 0u, 0u, 0u};
            if ((unsigned)gr < 256u)
                v = *(const uint4*)(Ub + gr * GSTR + sub * 8);
            *(uint4*)&T[row * TSTR + sub * 8] = v;
        }
    }
    __syncthreads();

    // ---- conv: wave w covers rows 32w..32w+31, cols 0..127 (4 strips share A-chunks) ----
    const int lane = tid & 63;
    const int w = tid >> 6;                            // band 0..3
    const int r32 = lane & 31;                         // A row i (C col j in epilogue)
    const int hk = lane >> 5;                          // k-chunk half

    const char* ab = (const char*)T + (32 * w + r32) * (TSTR * 2) + hk * 16;
    const bf16x8* tv = (const bf16x8*)tab;

    f32x16 acc[4];
    #pragma unroll
    for (int s = 0; s < 4; ++s)
        acc[s] = (f32x16){0.f,0.f,0.f,0.f,0.f,0.f,0.f,0.f,0.f,0.f,0.f,0.f,0.f,0.f,0.f,0.f};

    #pragma unroll 1
    for (int fr = 0; fr < 31; ++fr) {
        bf16x8 B[4];
        #pragma unroll
        for (int km = 0; km < 4; ++km)
            B[km] = tv[(fr * 4 + km) * 64 + lane];
        const char* u = ab + fr * (TSTR * 2);
        bf16x8 A[10];
        #pragma unroll
        for (int c = 0; c < 10; ++c)
            A[c] = *(const bf16x8*)(u + c * 32);
        // strip s uses chunks 2s..2s+3 with the SAME B-frags (Toeplitz shift identity)
        #pragma unroll
        for (int km = 0; km < 4; ++km)
            #pragma unroll
            for (int s = 0; s < 4; ++s)
                acc[s] = __builtin_amdgcn_mfma_f32_32x32x16_bf16(A[2 * s + km], B[km], acc[s], 0, 0, 0);
    }

    // ---- epilogue: bilinear downsample (rows in-lane via reg pairs, cols via shfl_xor) ----
    #pragma unroll
    for (int s = 0; s < 4; ++s) {
        int cc = 128 * bx + 32 * s + r32;              // conv col (C col j)
        const bool doout = (cc & 1) == 0;
        const int oj = cc >> 1;
        const float wxw = (float)oj * DNS - (float)cc;
        #pragma unroll
        for (int p = 0; p < 8; ++p) {
            int rpe = ((p & 1) << 1) + ((p >> 1) << 3) + 4 * hk;   // even C row of reg 2p
            int cre = 128 * by + 32 * w + rpe;
            int oi = cre >> 1;
            float wyw = (float)oi * DNS - (float)cre;
            float ae = acc[s][2 * p], ao = acc[s][2 * p + 1];
            float v = ae + (ao - ae) * wyw;
            float vr = __shfl_xor(v, 1, 64);
            if (doout) {
                float o = v + (vr - v) * wxw;
                out[((size_t)bc * 128 + oi) * 128 + oj] = o;
            }
        }
    }
}

// ---------- fallback (round-4 fused kernel) if ws too small for U ----------
#define FUSTR  120
#define FUROWS 158
__global__ __launch_bounds__(256)
void afa_mfma(const float* __restrict__ x, const unsigned short* __restrict__ tab,
              float* __restrict__ out) {
    __shared__ unsigned short Ut[FUROWS * FUSTR];
    const int tid = threadIdx.x;
    const int bx = blockIdx.x, by = blockIdx.y, bc = blockIdx.z;
    const float* __restrict__ xc = x + (size_t)bc * (INH * INH);
    const float UPS = (float)(127.0 / 255.0);
    const float DNS = (float)(255.0 / 127.0);
    const int pr0 = 128 * by, pc0 = 64 * bx;

    for (int idx = tid; idx < FUROWS * (FUSTR / 2); idx += 256) {
        int lr = idx / (FUSTR / 2);
        int lc0 = (idx - lr * (FUSTR / 2)) * 2;
        unsigned pack = 0;
        #pragma unroll
        for (int e = 0; e < 2; ++e) {
            int lc = lc0 + e;
            int ur = pr0 + lr - 15;
            int uc = pc0 + lc - 15;
            float val = 0.0f;
            if (lc < 96 && (unsigned)ur < 256u && (unsigned)uc < 256u)
                val = upsample_one(xc, ur, uc, UPS);
            pack |= (unsigned)f2bf(val) << (16 * e);
        }
        *(unsigned*)&Ut[lr * FUSTR + lc0] = pack;
    }
    __syncthreads();

    const int lane = tid & 63;
    const int w = tid >> 6;
    const int wxs = w & 1, wys = w >> 1;
    const int r32 = lane & 31;
    const int hk = lane >> 5;
    const char* ub = (const char*)Ut + (64 * wys + r32) * (FUSTR * 2) + (32 * wxs + 8 * hk) * 2;
    const bf16x8* tv = (const bf16x8*)tab;
    f32x16 acc0 = {0.f,0.f,0.f,0.f,0.f,0.f,0.f,0.f,0.f,0.f,0.f,0.f,0.f,0.f,0.f,0.f};
    f32x16 acc1 = acc0;

    #pragma unroll 1
    for (int fr = 0; fr < 31; ++fr) {
        bf16x8 B0 = tv[(fr * 4 + 0) * 64 + lane];
        bf16x8 B1 = tv[(fr * 4 + 1) * 64 + lane];
        bf16x8 B2 = tv[(fr * 4 + 2) * 64 + lane];
        bf16x8 B3 = tv[(fr * 4 + 3) * 64 + lane];
        const char* u0 = ub + fr * (FUSTR * 2);
        const char* u1 = u0 + 32 * (FUSTR * 2);
        bf16x8 a;
        a = *(const bf16x8*)(u0 + 0);
        acc0 = __builtin_amdgcn_mfma_f32_32x32x16_bf16(a, B0, acc0, 0, 0, 0);
        a = *(const bf16x8*)(u0 + 32);
        acc0 = __builtin_amdgcn_mfma_f32_32x32x16_bf16(a, B1, acc0, 0, 0, 0);
        a = *(const bf16x8*)(u0 + 64);
        acc0 = __builtin_amdgcn_mfma_f32_32x32x16_bf16(a, B2, acc0, 0, 0, 0);
        a = *(const bf16x8*)(u0 + 96);
        acc0 = __builtin_amdgcn_mfma_f32_32x32x16_bf16(a, B3, acc0, 0, 0, 0);
        a = *(const bf16x8*)(u1 + 0);
        acc1 = __builtin_amdgcn_mfma_f32_32x32x16_bf16(a, B0, acc1, 0, 0, 0);
        a = *(const bf16x8*)(u1 + 32);
        acc1 = __builtin_amdgcn_mfma_f32_32x32x16_bf16(a, B1, acc1, 0, 0, 0);
        a = *(const bf16x8*)(u1 + 64);
        acc1 = __builtin_amdgcn_mfma_f32_32x32x16_bf16(a, B2, acc1, 0, 0, 0);
        a = *(const bf16x8*)(u1 + 96);
        acc1 = __builtin_amdgcn_mfma_f32_32x32x16_bf16(a, B3, acc1, 0, 0, 0);
    }

    const int cc = 64 * bx + 32 * wxs + r32;
    const bool doout = (cc & 1) == 0;
    const int oj = cc >> 1;
    const float wxw = (float)oj * DNS - (float)cc;
    #pragma unroll
    for (int tt = 0; tt < 2; ++tt) {
        int cr0 = 128 * by + 64 * wys + 32 * tt;
        #pragma unroll
        for (int p = 0; p < 8; ++p) {
            int rpe = ((p & 1) << 1) + ((p >> 1) << 3) + 4 * hk;
            int cre = cr0 + rpe;
            int oi = cre >> 1;
            float wyw = (float)oi * DNS - (float)cre;
            float ae, ao;
            if (tt == 0) { ae = acc0[2 * p]; ao = acc0[2 * p + 1]; }
            else         { ae = acc1[2 * p]; ao = acc1[2 * p + 1]; }
            float v = ae + (ao - ae) * wyw;
            float vr = __shfl_xor(v, 1, 64);
            if (doout) {
                float o = v + (vr - v) * wxw;
                out[((size_t)bc * 128 + oi) * 128 + oj] = o;
            }
        }
    }
}

extern "C" void kernel_launch(void* const* d_in, const int* in_sizes, int n_in,
                              void* d_out, int out_size, void* d_ws, size_t ws_size,
                              hipStream_t stream) {
    const float* x    = (const float*)d_in[0];   // (8,64,128,128) f32
    const float* filt = (const float*)d_in[1];   // (31,31) f32
    float* out = (float*)d_out;                  // (8,64,128,128) f32

    unsigned short* tab = (unsigned short*)d_ws;                 // 124 KB @ offset 0
    const size_t U_OFF  = 131072;                                // 128 KB
    const size_t U_NEED = U_OFF + (size_t)512 * 256 * GSTR * 2;  // ~75.6 MB

    if (ws_size >= U_NEED) {
        unsigned short* U = (unsigned short*)((char*)d_ws + U_OFF);
        up_table<<<31 + 512 * 256 * 72 / 256, 256, 0, stream>>>(x, filt, U, tab);
        dim3 grid(2, 2, 8 * 64);
        conv_ds<<<grid, dim3(256), 0, stream>>>(U, tab, out);
    } else {
        build_table<<<31, 256, 0, stream>>>(filt, tab);
        dim3 grid(4, 2, 8 * 64);
        afa_mfma<<<grid, dim3(256), 0, stream>>>(x, tab, out);
    }
}

// Round 14
// 158.513 us; speedup vs baseline: 1.0844x; 1.0844x over previous
//
#include <hip/hip_runtime.h>
#include <hip/hip_bf16.h>

typedef __attribute__((ext_vector_type(8))) short bf16x8;
typedef __attribute__((ext_vector_type(16))) float f32x16;

#define INH   128
#define LEAK  0.01f
#define GSTR  288          // U row stride in bf16 (15 zero + 256 data + 17 zero)
#define TSTR  168          // LDS tile stride in bf16 (336B)
#define TROWS 94           // 64 conv rows + 30 halo

__device__ __forceinline__ unsigned short f2bf(float f) {
    __hip_bfloat16 h = __float2bfloat16(f);
    return *(unsigned short*)&h;
}

__device__ __forceinline__ float upsample_one(const float* __restrict__ xc,
                                              int ur, int uc, float UPS) {
    float cr = (float)ur * UPS;
    int r0 = (int)cr; if (r0 > 126) r0 = 126;
    float wr = cr - (float)r0;
    float cs = (float)uc * UPS;
    int s0 = (int)cs; if (s0 > 126) s0 = 126;
    float ws = cs - (float)s0;
    const float* p = xc + r0 * INH + s0;
    float a = p[0], b = p[1], c = p[INH], d = p[INH + 1];
    float top = a + (c - a) * wr;          // rows first (reference order)
    float bot = b + (d - b) * wr;
    float val = top + (bot - top) * ws;
    return (val > 0.0f) ? val : (LEAK * val);
}

// ---------- table builder (standalone, for fallback path) ----------
__global__ void build_table(const float* __restrict__ filt, unsigned short* __restrict__ tab) {
    int idx = blockIdx.x * 256 + threadIdx.x;          // (fr*4+c)*64 + lane
    if (idx >= 31 * 4 * 64) return;
    int lane = idx & 63, c = (idx >> 6) & 3, fr = idx >> 8;
    #pragma unroll
    for (int t = 0; t < 8; ++t) {
        int v = 16 * c + 8 * (lane >> 5) + t - (lane & 31);
        float f = (v >= 0 && v <= 30) ? filt[fr * 31 + v] : 0.0f;
        tab[idx * 8 + t] = f2bf(f);
    }
}

// ---------- kernel 1: table build (blocks 0..30) + upsample+act -> U (blocks 31..) ----------
__global__ __launch_bounds__(256)
void up_table(const float* __restrict__ x, const float* __restrict__ filt,
              unsigned short* __restrict__ U, unsigned short* __restrict__ tab) {
    const int tid = threadIdx.x;
    if (blockIdx.x < 31) {
        int idx = blockIdx.x * 256 + tid;
        if (idx >= 31 * 4 * 64) return;
        int lane = idx & 63, c = (idx >> 6) & 3, fr = idx >> 8;
        #pragma unroll
        for (int t = 0; t < 8; ++t) {
            int v = 16 * c + 8 * (lane >> 5) + t - (lane & 31);
            float f = (v >= 0 && v <= 30) ? filt[fr * 31 + v] : 0.0f;
            tab[idx * 8 + t] = f2bf(f);
        }
        return;
    }
    const float UPS = (float)(127.0 / 255.0);
    int idx = (blockIdx.x - 31) * 256 + tid;           // unit = 4 bf16 cols (8 B)
    int bc = idx / (256 * 72);
    int rem = idx - bc * (256 * 72);
    int r = rem / 72;
    int c4 = (rem - r * 72) * 4;
    const float* __restrict__ xc = x + (size_t)bc * (INH * INH);
    unsigned short o[4];
    #pragma unroll
    for (int e = 0; e < 4; ++e) {
        int uc = c4 + e - 15;
        float val = 0.0f;
        if ((unsigned)uc < 256u) val = upsample_one(xc, r, uc, UPS);
        o[e] = f2bf(val);
    }
    *(uint2*)&U[((size_t)bc * 256 + r) * GSTR + c4] = *(const uint2*)o;
}

// inline-asm loads: fixed issue order, un-collapsible register sets
#define DSRD(dst, addr, OFF) \
    asm volatile("ds_read_b128 %0, %1 offset:" #OFF : "=v"(dst) : "v"(addr))
#define GLB(dst, p, OFF) \
    asm volatile("global_load_dwordx4 %0, %1, off offset:" #OFF : "=v"(dst) : "v"(p))

// issue one fr's fragment set: 6 LDS A-chunks + 4 global B-frags
#define ISSUE(ua, pbp, A0,A1,A2,A3,A4,A5,B0,B1,B2,B3) { \
    DSRD(A0, ua, 0);   DSRD(A1, ua, 32);  DSRD(A2, ua, 64); \
    DSRD(A3, ua, 96);  DSRD(A4, ua, 128); DSRD(A5, ua, 160); \
    GLB(B0, pbp, 0); GLB(B1, pbp, 1024); GLB(B2, pbp, 2048); GLB(B3, pbp, 3072); }

// counted waits; sched_barrier(0) seals regions both directions (rule #18)
#define WAIT_128 { asm volatile("s_waitcnt vmcnt(8) lgkmcnt(12)"); __builtin_amdgcn_sched_barrier(0); }
#define WAIT_64  { asm volatile("s_waitcnt vmcnt(4) lgkmcnt(6)");  __builtin_amdgcn_sched_barrier(0); }
#define WAIT_00  { asm volatile("s_waitcnt vmcnt(0) lgkmcnt(0)");  __builtin_amdgcn_sched_barrier(0); }

// strip0 uses chunks 0..3, strip1 uses chunks 2..5 with the SAME B-frags
#define MFMA8(A0,A1,A2,A3,A4,A5,B0,B1,B2,B3) { \
    acc0 = __builtin_amdgcn_mfma_f32_32x32x16_bf16(A0, B0, acc0, 0, 0, 0); \
    acc1 = __builtin_amdgcn_mfma_f32_32x32x16_bf16(A2, B0, acc1, 0, 0, 0); \
    acc0 = __builtin_amdgcn_mfma_f32_32x32x16_bf16(A1, B1, acc0, 0, 0, 0); \
    acc1 = __builtin_amdgcn_mfma_f32_32x32x16_bf16(A3, B1, acc1, 0, 0, 0); \
    acc0 = __builtin_amdgcn_mfma_f32_32x32x16_bf16(A2, B2, acc0, 0, 0, 0); \
    acc1 = __builtin_amdgcn_mfma_f32_32x32x16_bf16(A4, B2, acc1, 0, 0, 0); \
    acc0 = __builtin_amdgcn_mfma_f32_32x32x16_bf16(A3, B3, acc0, 0, 0, 0); \
    acc1 = __builtin_amdgcn_mfma_f32_32x32x16_bf16(A5, B3, acc1, 0, 0, 0); }

// ---------- kernel 2: copy-stage -> MFMA conv (3-deep asm pipeline) -> downsample ----------
__global__ __launch_bounds__(256, 3)
void conv_ds(const unsigned short* __restrict__ U, const unsigned short* __restrict__ tab,
             float* __restrict__ out) {
    __shared__ unsigned short T[TROWS * TSTR];         // 31584 B
    const int tid = threadIdx.x;
    const int bx = blockIdx.x;                         // 0..1 (128 conv cols)
    const int by = blockIdx.y;                         // 0..3 (64 conv rows)
    const int bc = blockIdx.z;                         // 0..511
    const float DNS = (float)(255.0 / 127.0);
    const int pr0 = 64 * by;
    const unsigned short* __restrict__ Ub = U + (size_t)bc * 256 * GSTR + bx * 128;

    // ---- stage: 94 rows x 20 uint4 (160 bf16 cols), vertical pad via row predicate ----
    #pragma unroll
    for (int k = 0; k < 8; ++k) {
        int c = tid + k * 256;
        if (c < TROWS * 20) {
            int row = c / 20;
            int sub = c - row * 20;
            int gr = pr0 + row - 15;
            uint4 v = {0u, 0u, 0u, 0u};
            if ((unsigned)gr < 256u)
                v = *(const uint4*)(Ub + gr * GSTR + sub * 8);
            *(uint4*)&T[row * TSTR + sub * 8] = v;
        }
    }
    __syncthreads();

    // ---- conv: wave = 32 rows x 64 cols (2 col strips sharing A-chunks 2..3) ----
    const int lane = tid & 63;
    const int w = tid >> 6;
    const int wxs = w & 1;                             // col half within block
    const int band = w >> 1;                           // 32-row band within block
    const int r32 = lane & 31;                         // A row i (C col j in epilogue)
    const int hk = lane >> 5;                          // k-chunk half

    const char* ab = (const char*)T + (32 * band + r32) * (TSTR * 2) + (64 * wxs + 8 * hk) * 2;
    const unsigned ux = (unsigned)(unsigned long long)(const void*)ab;
    const char* pb0 = (const char*)tab + (size_t)lane * 16;

    f32x16 acc0 = {0.f,0.f,0.f,0.f,0.f,0.f,0.f,0.f,0.f,0.f,0.f,0.f,0.f,0.f,0.f,0.f};
    f32x16 acc1 = acc0;

    bf16x8 xA0,xA1,xA2,xA3,xA4,xA5,xB0,xB1,xB2,xB3;
    bf16x8 yA0,yA1,yA2,yA3,yA4,yA5,yB0,yB1,yB2,yB3;
    bf16x8 zA0,zA1,zA2,zA3,zA4,zA5,zB0,zB1,zB2,zB3;

    // prologue: issue fr 0,1,2
    ISSUE(ux,           pb0,         xA0,xA1,xA2,xA3,xA4,xA5,xB0,xB1,xB2,xB3);
    ISSUE(ux + 336,     pb0 + 4096,  yA0,yA1,yA2,yA3,yA4,yA5,yB0,yB1,yB2,yB3);
    ISSUE(ux + 672,     pb0 + 8192,  zA0,zA1,zA2,zA3,zA4,zA5,zB0,zB1,zB2,zB3);

    #pragma unroll 1
    for (int f = 0; f < 27; f += 3) {                  // 9 iters: process fr 0..26
        unsigned u3 = ux + (unsigned)(f + 3) * 336;
        const char* p3 = pb0 + (size_t)(f + 3) * 4096;
        WAIT_128;                                      // x (fr f) landed; y,z in flight
        MFMA8(xA0,xA1,xA2,xA3,xA4,xA5,xB0,xB1,xB2,xB3);
        ISSUE(u3, p3, xA0,xA1,xA2,xA3,xA4,xA5,xB0,xB1,xB2,xB3);
        WAIT_128;                                      // y (fr f+1) landed
        MFMA8(yA0,yA1,yA2,yA3,yA4,yA5,yB0,yB1,yB2,yB3);
        ISSUE(u3 + 336, p3 + 4096, yA0,yA1,yA2,yA3,yA4,yA5,yB0,yB1,yB2,yB3);
        WAIT_128;                                      // z (fr f+2) landed
        MFMA8(zA0,zA1,zA2,zA3,zA4,zA5,zB0,zB1,zB2,zB3);
        ISSUE(u3 + 672, p3 + 8192, zA0,zA1,zA2,zA3,zA4,zA5,zB0,zB1,zB2,zB3);
    }
    // drain: fr 27(x), 28(y), 29(z) in flight; issue 30 into x
    WAIT_128;
    MFMA8(xA0,xA1,xA2,xA3,xA4,xA5,xB0,xB1,xB2,xB3);    // fr 27
    ISSUE(ux + 30u * 336, pb0 + 30 * 4096, xA0,xA1,xA2,xA3,xA4,xA5,xB0,xB1,xB2,xB3);
    WAIT_128;
    MFMA8(yA0,yA1,yA2,yA3,yA4,yA5,yB0,yB1,yB2,yB3);    // fr 28
    WAIT_64;
    MFMA8(zA0,zA1,zA2,zA3,zA4,zA5,zB0,zB1,zB2,zB3);    // fr 29
    WAIT_00;
    MFMA8(xA0,xA1,xA2,xA3,xA4,xA5,xB0,xB1,xB2,xB3);    // fr 30

    // ---- epilogue: bilinear downsample (rows in-lane via reg pairs, cols via shfl_xor) ----
    #pragma unroll
    for (int s = 0; s < 2; ++s) {
        int cc = 128 * bx + 64 * wxs + 32 * s + r32;    // conv col (C col j)
        const bool doout = (cc & 1) == 0;
        const int oj = cc >> 1;
        const float wxw = (float)oj * DNS - (float)cc;
        #pragma unroll
        for (int p = 0; p < 8; ++p) {
            int rpe = ((p & 1) << 1) + ((p >> 1) << 3) + 4 * hk;   // even C row of reg 2p
            int cre = 64 * by + 32 * band + rpe;
            int oi = cre >> 1;
            float wyw = (float)oi * DNS - (float)cre;
            float ae, ao;
            if (s == 0) { ae = acc0[2 * p]; ao = acc0[2 * p + 1]; }
            else        { ae = acc1[2 * p]; ao = acc1[2 * p + 1]; }
            float v = ae + (ao - ae) * wyw;
            float vr = __shfl_xor(v, 1, 64);
            if (doout) {
                float o = v + (vr - v) * wxw;
                out[((size_t)bc * 128 + oi) * 128 + oj] = o;
            }
        }
    }
}

// ---------- fallback (round-4 fused kernel) if ws too small for U ----------
#define FUSTR  120
#define FUROWS 158
__global__ __launch_bounds__(256)
void afa_mfma(const float* __restrict__ x, const unsigned short* __restrict__ tab,
              float* __restrict__ out) {
    __shared__ unsigned short Ut[FUROWS * FUSTR];
    const int tid = threadIdx.x;
    const int bx = blockIdx.x, by = blockIdx.y, bc = blockIdx.z;
    const float* __restrict__ xc = x + (size_t)bc * (INH * INH);
    const float UPS = (float)(127.0 / 255.0);
    const float DNS = (float)(255.0 / 127.0);
    const int pr0 = 128 * by, pc0 = 64 * bx;

    for (int idx = tid; idx < FUROWS * (FUSTR / 2); idx += 256) {
        int lr = idx / (FUSTR / 2);
        int lc0 = (idx - lr * (FUSTR / 2)) * 2;
        unsigned pack = 0;
        #pragma unroll
        for (int e = 0; e < 2; ++e) {
            int lc = lc0 + e;
            int ur = pr0 + lr - 15;
            int uc = pc0 + lc - 15;
            float val = 0.0f;
            if (lc < 96 && (unsigned)ur < 256u && (unsigned)uc < 256u)
                val = upsample_one(xc, ur, uc, UPS);
            pack |= (unsigned)f2bf(val) << (16 * e);
        }
        *(unsigned*)&Ut[lr * FUSTR + lc0] = pack;
    }
    __syncthreads();

    const int lane = tid & 63;
    const int w = tid >> 6;
    const int wxs = w & 1, wys = w >> 1;
    const int r32 = lane & 31;
    const int hk = lane >> 5;
    const char* ub = (const char*)Ut + (64 * wys + r32) * (FUSTR * 2) + (32 * wxs + 8 * hk) * 2;
    const bf16x8* tv = (const bf16x8*)tab;
    f32x16 acc0 = {0.f,0.f,0.f,0.f,0.f,0.f,0.f,0.f,0.f,0.f,0.f,0.f,0.f,0.f,0.f,0.f};
    f32x16 acc1 = acc0;

    #pragma unroll 1
    for (int fr = 0; fr < 31; ++fr) {
        bf16x8 B0 = tv[(fr * 4 + 0) * 64 + lane];
        bf16x8 B1 = tv[(fr * 4 + 1) * 64 + lane];
        bf16x8 B2 = tv[(fr * 4 + 2) * 64 + lane];
        bf16x8 B3 = tv[(fr * 4 + 3) * 64 + lane];
        const char* u0 = ub + fr * (FUSTR * 2);
        const char* u1 = u0 + 32 * (FUSTR * 2);
        bf16x8 a;
        a = *(const bf16x8*)(u0 + 0);
        acc0 = __builtin_amdgcn_mfma_f32_32x32x16_bf16(a, B0, acc0, 0, 0, 0);
        a = *(const bf16x8*)(u0 + 32);
        acc0 = __builtin_amdgcn_mfma_f32_32x32x16_bf16(a, B1, acc0, 0, 0, 0);
        a = *(const bf16x8*)(u0 + 64);
        acc0 = __builtin_amdgcn_mfma_f32_32x32x16_bf16(a, B2, acc0, 0, 0, 0);
        a = *(const bf16x8*)(u0 + 96);
        acc0 = __builtin_amdgcn_mfma_f32_32x32x16_bf16(a, B3, acc0, 0, 0, 0);
        a = *(const bf16x8*)(u1 + 0);
        acc1 = __builtin_amdgcn_mfma_f32_32x32x16_bf16(a, B0, acc1, 0, 0, 0);
        a = *(const bf16x8*)(u1 + 32);
        acc1 = __builtin_amdgcn_mfma_f32_32x32x16_bf16(a, B1, acc1, 0, 0, 0);
        a = *(const bf16x8*)(u1 + 64);
        acc1 = __builtin_amdgcn_mfma_f32_32x32x16_bf16(a, B2, acc1, 0, 0, 0);
        a = *(const bf16x8*)(u1 + 96);
        acc1 = __builtin_amdgcn_mfma_f32_32x32x16_bf16(a, B3, acc1, 0, 0, 0);
    }

    const int cc = 64 * bx + 32 * wxs + r32;
    const bool doout = (cc & 1) == 0;
    const int oj = cc >> 1;
    const float wxw = (float)oj * DNS - (float)cc;
    #pragma unroll
    for (int tt = 0; tt < 2; ++tt) {
        int cr0 = 128 * by + 64 * wys + 32 * tt;
        #pragma unroll
        for (int p = 0; p < 8; ++p) {
            int rpe = ((p & 1) << 1) + ((p >> 1) << 3) + 4 * hk;
            int cre = cr0 + rpe;
            int oi = cre >> 1;
            float wyw = (float)oi * DNS - (float)cre;
            float ae, ao;
            if (tt == 0) { ae = acc0[2 * p]; ao = acc0[2 * p + 1]; }
            else         { ae = acc1[2 * p]; ao = acc1[2 * p + 1]; }
            float v = ae + (ao - ae) * wyw;
            float vr = __shfl_xor(v, 1, 64);
            if (doout) {
                float o = v + (vr - v) * wxw;
                out[((size_t)bc * 128 + oi) * 128 + oj] = o;
            }
        }
    }
}

extern "C" void kernel_launch(void* const* d_in, const int* in_sizes, int n_in,
                              void* d_out, int out_size, void* d_ws, size_t ws_size,
                              hipStream_t stream) {
    const float* x    = (const float*)d_in[0];   // (8,64,128,128) f32
    const float* filt = (const float*)d_in[1];   // (31,31) f32
    float* out = (float*)d_out;                  // (8,64,128,128) f32

    unsigned short* tab = (unsigned short*)d_ws;                 // 124 KB @ offset 0
    const size_t U_OFF  = 131072;                                // 128 KB
    const size_t U_NEED = U_OFF + (size_t)512 * 256 * GSTR * 2;  // ~75.6 MB

    if (ws_size >= U_NEED) {
        unsigned short* U = (unsigned short*)((char*)d_ws + U_OFF);
        up_table<<<31 + 512 * 256 * 72 / 256, 256, 0, stream>>>(x, filt, U, tab);
        dim3 grid(2, 4, 8 * 64);
        conv_ds<<<grid, dim3(256), 0, stream>>>(U, tab, out);
    } else {
        build_table<<<31, 256, 0, stream>>>(filt, tab);
        dim3 grid(4, 2, 8 * 64);
        afa_mfma<<<grid, dim3(256), 0, stream>>>(x, tab, out);
    }
}